// Round 2
// baseline (297.806 us; speedup 1.0000x reference)
//
#include <hip/hip_runtime.h>
#include <stdint.h>

#define NROW 8192
#define LOG2E 1.4426950408889634f
#define ALPHA 0.3f

// workspace float-index offsets
#define WA1_OFF 0
#define WA2_OFF 512
#define S1_OFF 1024
#define S2_OFF (1024 + 8192)
#define SCAL_OFF (S2_OFF + 8192)
// workspace byte offsets
#define PQB_OFF 70656                 // 16B-aligned, past scalars
#define PQB_BYTES (256 * 40960)       // 256 k-blocks x [2][320 cols][32 k] f16
#define PART_OFF (PQB_OFF + PQB_BYTES)

typedef _Float16 f16x8 __attribute__((ext_vector_type(8)));
typedef __fp16 fp16x2 __attribute__((ext_vector_type(2)));
typedef float f32x4 __attribute__((ext_vector_type(4)));

union HPack { fp16x2 h2[4]; f16x8 v; uint32_t u[4]; };
union HBits { _Float16 h[2]; uint32_t u; };

__device__ __forceinline__ int swz(int col, int g) { return (g + (col >> 1)) & 3; }

// ---------------- K0: wa1/wa2 = W @ a halves (wave-per-row dot) ----------------
__global__ void k_wa(const float* __restrict__ Wm, const float* __restrict__ a,
                     float* __restrict__ wsf) {
  int r = blockIdx.x * 4 + (threadIdx.x >> 6);
  int ln = threadIdx.x & 63;
  if (r >= 300) return;
  float a1 = 0.f, a2 = 0.f;
  for (int c = ln; c < 300; c += 64) {
    float w = Wm[r * 300 + c];
    a1 += w * a[c];
    a2 += w * a[300 + c];
  }
  for (int o = 32; o; o >>= 1) { a1 += __shfl_down(a1, o); a2 += __shfl_down(a2, o); }
  if (!ln) { wsf[WA1_OFF + r] = a1; wsf[WA2_OFF + r] = a2; }
}

// ---------------- K1: s1/s2 = inp @ wa (scaled by log2e) ----------------
__global__ void k_s12(const float* __restrict__ inp, float* __restrict__ wsf) {
  int row = blockIdx.x * 4 + (threadIdx.x >> 6);
  int ln = threadIdx.x & 63;
  const float* ip = inp + (size_t)row * 300;
  float a1 = 0.f, a2 = 0.f;
  for (int c = ln; c < 300; c += 64) {
    float v = ip[c];
    a1 += v * wsf[WA1_OFF + c];
    a2 += v * wsf[WA2_OFF + c];
  }
  for (int o = 32; o; o >>= 1) { a1 += __shfl_down(a1, o); a2 += __shfl_down(a2, o); }
  if (!ln) { wsf[S1_OFF + row] = a1 * LOG2E; wsf[S2_OFF + row] = a2 * LOG2E; }
}

// ---------------- K2: global max/min of s2' ----------------
__global__ void k_minmax(float* __restrict__ wsf) {
  int t = threadIdx.x;
  float mx = -3e38f, mn = 3e38f;
  for (int i = t; i < NROW; i += 1024) {
    float v = wsf[S2_OFF + i];
    mx = fmaxf(mx, v); mn = fminf(mn, v);
  }
  for (int o = 32; o; o >>= 1) {
    mx = fmaxf(mx, __shfl_down(mx, o));
    mn = fminf(mn, __shfl_down(mn, o));
  }
  __shared__ float sm[32];
  int wv = t >> 6, ln = t & 63;
  if (!ln) { sm[wv] = mx; sm[16 + wv] = mn; }
  __syncthreads();
  if (!t) {
    float M = sm[0], m = sm[16];
    for (int q = 1; q < 16; q++) { M = fmaxf(M, sm[q]); m = fminf(m, sm[16 + q]); }
    wsf[SCAL_OFF] = M; wsf[SCAL_OFF + 1] = m;
  }
}

// ---------------- K3: P/Q = inp @ wtrans halves -> blocked swizzled f16 ----------------
// PQB[kb][pq][col(320)][kgrp swizzled(4)][8] f16 ; col 300 = ones (Z column), 301..303 = 0
__global__ __launch_bounds__(640) void k_wt(const float* __restrict__ inp,
                                            const float* __restrict__ wt,
                                            uint16_t* __restrict__ pqb) {
  __shared__ float L[300 * 36];
  const int kb = blockIdx.x;
  const int t = threadIdx.x;
  const float* src = inp + (size_t)kb * 32 * 300;
  for (int idx = t; idx < 9600; idx += 640) {
    int j = idx / 300;
    int c = idx - j * 300;
    L[c * 36 + j] = src[idx];
  }
  __syncthreads();
  if (t < 608) {
    const int pq = (t >= 304) ? 1 : 0;
    const int f = t - pq * 304;
    float acc[32];
    if (f < 300) {
      #pragma unroll
      for (int q = 0; q < 32; q++) acc[q] = 0.f;
      const float* wcol = wt + (size_t)pq * 90000 + f;
      for (int c = 0; c < 300; c++) {
        float wv = wcol[(size_t)c * 300];
        const float4* lp = (const float4*)(L + c * 36);
        #pragma unroll
        for (int q = 0; q < 8; q++) {
          float4 v = lp[q];
          acc[q * 4 + 0] += v.x * wv;
          acc[q * 4 + 1] += v.y * wv;
          acc[q * 4 + 2] += v.z * wv;
          acc[q * 4 + 3] += v.w * wv;
        }
      }
    } else {
      float cv = (f == 300) ? 1.0f : 0.0f;
      #pragma unroll
      for (int q = 0; q < 32; q++) acc[q] = cv;
    }
    uint16_t* dst = pqb + (size_t)kb * 20480 + (size_t)pq * 10240 + (size_t)f * 32;
    #pragma unroll
    for (int g = 0; g < 4; g++) {
      const int gs = swz(f, g);
      uint32_t* d32 = (uint32_t*)(dst + gs * 8);
      #pragma unroll
      for (int i = 0; i < 4; i++) {
        HBits hb;
        hb.h[0] = (_Float16)acc[g * 8 + 2 * i];
        hb.h[1] = (_Float16)acc[g * 8 + 2 * i + 1];
        d32[i] = hb.u;
      }
    }
  }
}

// ---------------- K4: fused masked-double-softmax @ [P|Q] (unnormalized + Z col) ----------------
__global__ __launch_bounds__(512, 2) void k_main(const int* __restrict__ adj,
                                                 const float* __restrict__ wsf,
                                                 const uint16_t* __restrict__ pqb,
                                                 float* __restrict__ part, int nsplit) {
  __shared__ __align__(16) uint16_t Bsm[2 * 320 * 32];  // 40960 B
  const int bid = blockIdx.x;
  const int mblk = bid / nsplit;
  const int ks = bid - mblk * nsplit;
  const int tid = threadIdx.x;
  const int w = tid >> 6, lane = tid & 63;
  const int lr = lane & 15, lg = lane >> 4;
  const int row = mblk * 128 + w * 16 + lr;
  const float c1 = wsf[S1_OFF + row];
  const float s2mx = wsf[SCAL_OFF];
  const float s2mn = wsf[SCAL_OFF + 1];
  float t1 = c1 + s2mx; const float mxp = fmaxf(t1, ALPHA * t1);  // >= all e' in row
  float t2 = c1 + s2mn; const float mn2 = fmaxf(t2, ALPHA * t2);  // <= all e' in row
  const int kcnt = NROW / nsplit;
  const int k0 = ks * kcnt;
  const int ksteps = kcnt >> 5;
  const int* adjrow = adj + (size_t)row * NROW;
  f32x4 accP[19], accN[19];
  const f32x4 zero = {0.f, 0.f, 0.f, 0.f};
  #pragma unroll
  for (int ct = 0; ct < 19; ct++) { accP[ct] = zero; accN[ct] = zero; }
  const char* smc = (const char*)Bsm;

  for (int s = 0; s < ksteps; s++) {
    const int kk = k0 + s * 32;
    const char* tile = (const char*)(pqb + (size_t)(kk >> 5) * 20480);
    #pragma unroll
    for (int it = 0; it < 5; it++) {
      int off = (w * 5 + it) * 1024;
      __builtin_amdgcn_global_load_lds(
          (const __attribute__((address_space(1))) void*)(tile + off + lane * 16),
          (__attribute__((address_space(3))) void*)((char*)Bsm + off),
          16, 0, 0);
    }
    const int kw = kk + lg * 8;
    const int4 a0 = *(const int4*)(adjrow + kw);
    const int4 a1 = *(const int4*)(adjrow + kw + 4);
    const float4 s0 = *(const float4*)(wsf + S2_OFF + kw);
    const float4 s1v = *(const float4*)(wsf + S2_OFF + kw + 4);
    float se[8] = {s0.x, s0.y, s0.z, s0.w, s1v.x, s1v.y, s1v.z, s1v.w};
    int am[8] = {a0.x, a0.y, a0.z, a0.w, a1.x, a1.y, a1.z, a1.w};
    HPack up, un;
    #pragma unroll
    for (int e = 0; e < 8; e += 2) {
      float ea = c1 + se[e];     ea = fmaxf(ea, ALPHA * ea);   // lrelu (log2 domain)
      float eb = c1 + se[e + 1]; eb = fmaxf(eb, ALPHA * eb);
      float pa = exp2f(ea - mxp);
      float pb = exp2f(eb - mxp);
      float na = exp2f(mn2 - ea);
      float nb = exp2f(mn2 - eb);
      pa = am[e] ? pa : 0.0f;     na = am[e] ? na : 0.0f;
      pb = am[e + 1] ? pb : 0.0f; nb = am[e + 1] ? nb : 0.0f;
      up.h2[e >> 1] = __builtin_amdgcn_cvt_pkrtz(pa, pb);
      un.h2[e >> 1] = __builtin_amdgcn_cvt_pkrtz(na, nb);
    }
    __syncthreads();  // staged tile ready (vmcnt drained)
    #pragma unroll
    for (int ct = 0; ct < 19; ct++) {
      const int col = ct * 16 + lr;
      const int gp = swz(col, lg);
      f16x8 bP = *(const f16x8*)(smc + col * 64 + gp * 16);
      f16x8 bN = *(const f16x8*)(smc + 20480 + col * 64 + gp * 16);
      accP[ct] = __builtin_amdgcn_mfma_f32_16x16x32_f16(up.v, bP, accP[ct], 0, 0, 0);
      accN[ct] = __builtin_amdgcn_mfma_f32_16x16x32_f16(un.v, bN, accN[ct], 0, 0, 0);
    }
    __syncthreads();  // protect LDS before next stage
  }

  const int orow = mblk * 128 + w * 16 + lg * 4;
  float* pbase = part + ((size_t)ks * NROW + orow) * 608;
  #pragma unroll
  for (int ct = 0; ct < 19; ct++) {
    const int col = ct * 16 + lr;
    #pragma unroll
    for (int r = 0; r < 4; r++) {
      pbase[(size_t)r * 608 + col] = accP[ct][r];
      pbase[(size_t)r * 608 + 304 + col] = accN[ct][r];
    }
  }
}

// ---------------- K5: reduce k-splits, normalize, elu ----------------
__global__ void k_final(const float* __restrict__ part, float* __restrict__ out, int nsplit) {
  const int i = blockIdx.x;
  const int t = threadIdx.x;
  if (t >= 300) return;
  float sp = 0.f, sn = 0.f, zp = 0.f, zn = 0.f;
  for (int s = 0; s < nsplit; s++) {
    const float* p = part + ((size_t)s * NROW + i) * 608;
    sp += p[t];
    sn += p[304 + t];
    zp += p[300];
    zn += p[604];
  }
  float x = sp / zp - sn / zn;
  out[(size_t)i * 300 + t] = (x > 0.f) ? x : (exp2f(x * LOG2E) - 1.0f);
}

extern "C" void kernel_launch(void* const* d_in, const int* in_sizes, int n_in,
                              void* d_out, int out_size, void* d_ws, size_t ws_size,
                              hipStream_t stream) {
  const float* inp = (const float*)d_in[0];
  const int* adj = (const int*)d_in[1];
  const float* Wm = (const float*)d_in[2];
  const float* a = (const float*)d_in[3];
  const float* wt = (const float*)d_in[4];
  float* out = (float*)d_out;
  float* wsf = (float*)d_ws;
  uint16_t* pqb = (uint16_t*)((char*)d_ws + PQB_OFF);
  float* part = (float*)((char*)d_ws + PART_OFF);

  int nsplit = 4;
  while (nsplit > 1 &&
         (size_t)PART_OFF + (size_t)nsplit * NROW * 608 * 4 > ws_size)
    nsplit >>= 1;

  k_wa<<<75, 256, 0, stream>>>(Wm, a, wsf);
  k_s12<<<NROW / 4, 256, 0, stream>>>(inp, wsf);
  k_minmax<<<1, 1024, 0, stream>>>(wsf);
  k_wt<<<256, 640, 0, stream>>>(inp, wt, pqb);
  k_main<<<64 * nsplit, 512, 0, stream>>>(adj, wsf, pqb, part, nsplit);
  k_final<<<NROW, 320, 0, stream>>>(part, out, nsplit);
}

// Round 3
// 264.854 us; speedup vs baseline: 1.1244x; 1.1244x over previous
//
#include <hip/hip_runtime.h>
#include <stdint.h>

#define NROW 8192
#define LOG2E 1.4426950408889634f
#define ALPHA 0.3f

// workspace float-index offsets
#define WA1_OFF 0
#define WA2_OFF 512
#define S1_OFF 1024
#define S2_OFF (1024 + 8192)
#define SCAL_OFF (S2_OFF + 8192)
// workspace byte offsets
#define PQB_OFF 70656                 // 16B-aligned, past scalars
#define PQB_BYTES (256 * 40960)       // 256 k-blocks x [2][320 cols][32 k] f16
#define PART_OFF (PQB_OFF + PQB_BYTES)

typedef _Float16 f16x8 __attribute__((ext_vector_type(8)));
typedef __fp16 fp16x2 __attribute__((ext_vector_type(2)));
typedef float f32x4 __attribute__((ext_vector_type(4)));

union HPack { fp16x2 h2[4]; f16x8 v; uint32_t u[4]; };
union HBits { _Float16 h[2]; uint32_t u; };

__device__ __forceinline__ int swz(int col, int g) { return (g + (col >> 1)) & 3; }

// ---------------- K0: wa1/wa2 = W @ a halves (wave-per-row dot) ----------------
__global__ void k_wa(const float* __restrict__ Wm, const float* __restrict__ a,
                     float* __restrict__ wsf) {
  int r = blockIdx.x * 4 + (threadIdx.x >> 6);
  int ln = threadIdx.x & 63;
  if (r >= 300) return;
  float a1 = 0.f, a2 = 0.f;
  for (int c = ln; c < 300; c += 64) {
    float w = Wm[r * 300 + c];
    a1 += w * a[c];
    a2 += w * a[300 + c];
  }
  for (int o = 32; o; o >>= 1) { a1 += __shfl_down(a1, o); a2 += __shfl_down(a2, o); }
  if (!ln) { wsf[WA1_OFF + r] = a1; wsf[WA2_OFF + r] = a2; }
}

// ---------------- K1: s1/s2 = inp @ wa (scaled by log2e) ----------------
__global__ void k_s12(const float* __restrict__ inp, float* __restrict__ wsf) {
  int row = blockIdx.x * 4 + (threadIdx.x >> 6);
  int ln = threadIdx.x & 63;
  const float* ip = inp + (size_t)row * 300;
  float a1 = 0.f, a2 = 0.f;
  for (int c = ln; c < 300; c += 64) {
    float v = ip[c];
    a1 += v * wsf[WA1_OFF + c];
    a2 += v * wsf[WA2_OFF + c];
  }
  for (int o = 32; o; o >>= 1) { a1 += __shfl_down(a1, o); a2 += __shfl_down(a2, o); }
  if (!ln) { wsf[S1_OFF + row] = a1 * LOG2E; wsf[S2_OFF + row] = a2 * LOG2E; }
}

// ---------------- K2: global max/min of s2' ----------------
__global__ void k_minmax(float* __restrict__ wsf) {
  int t = threadIdx.x;
  float mx = -3e38f, mn = 3e38f;
  for (int i = t; i < NROW; i += 1024) {
    float v = wsf[S2_OFF + i];
    mx = fmaxf(mx, v); mn = fminf(mn, v);
  }
  for (int o = 32; o; o >>= 1) {
    mx = fmaxf(mx, __shfl_down(mx, o));
    mn = fminf(mn, __shfl_down(mn, o));
  }
  __shared__ float sm[32];
  int wv = t >> 6, ln = t & 63;
  if (!ln) { sm[wv] = mx; sm[16 + wv] = mn; }
  __syncthreads();
  if (!t) {
    float M = sm[0], m = sm[16];
    for (int q = 1; q < 16; q++) { M = fmaxf(M, sm[q]); m = fminf(m, sm[16 + q]); }
    wsf[SCAL_OFF] = M; wsf[SCAL_OFF + 1] = m;
  }
}

// ---------------- K3: P/Q = inp @ wtrans halves -> blocked swizzled f16 ----------------
// PQB[kb][pq][col(320)][kgrp swizzled(4)][8] f16 ; col 300 = ones (Z column), 301..303 = 0
__global__ __launch_bounds__(640) void k_wt(const float* __restrict__ inp,
                                            const float* __restrict__ wt,
                                            uint16_t* __restrict__ pqb) {
  __shared__ float L[300 * 36];
  const int kb = blockIdx.x;
  const int t = threadIdx.x;
  const float* src = inp + (size_t)kb * 32 * 300;
  for (int idx = t; idx < 9600; idx += 640) {
    int j = idx / 300;
    int c = idx - j * 300;
    L[c * 36 + j] = src[idx];
  }
  __syncthreads();
  if (t < 608) {
    const int pq = (t >= 304) ? 1 : 0;
    const int f = t - pq * 304;
    float acc[32];
    if (f < 300) {
      #pragma unroll
      for (int q = 0; q < 32; q++) acc[q] = 0.f;
      const float* wcol = wt + (size_t)pq * 90000 + f;
      for (int c = 0; c < 300; c++) {
        float wv = wcol[(size_t)c * 300];
        const float4* lp = (const float4*)(L + c * 36);
        #pragma unroll
        for (int q = 0; q < 8; q++) {
          float4 v = lp[q];
          acc[q * 4 + 0] += v.x * wv;
          acc[q * 4 + 1] += v.y * wv;
          acc[q * 4 + 2] += v.z * wv;
          acc[q * 4 + 3] += v.w * wv;
        }
      }
    } else {
      float cv = (f == 300) ? 1.0f : 0.0f;
      #pragma unroll
      for (int q = 0; q < 32; q++) acc[q] = cv;
    }
    uint16_t* dst = pqb + (size_t)kb * 20480 + (size_t)pq * 10240 + (size_t)f * 32;
    #pragma unroll
    for (int g = 0; g < 4; g++) {
      const int gs = swz(f, g);
      uint32_t* d32 = (uint32_t*)(dst + gs * 8);
      #pragma unroll
      for (int i = 0; i < 4; i++) {
        HBits hb;
        hb.h[0] = (_Float16)acc[g * 8 + 2 * i];
        hb.h[1] = (_Float16)acc[g * 8 + 2 * i + 1];
        d32[i] = hb.u;
      }
    }
  }
}

// ---------------- K4: fused masked-double-softmax @ [P|Q] ----------------
// 2-phase pipeline: double-buffered B-tile, adj/s2 register prefetch,
// ONE __syncthreads per k-step. 64 rows/block, 4 waves, 2 blocks/CU.
__global__ __launch_bounds__(256, 2) void k_main(const int* __restrict__ adj,
                                                 const float* __restrict__ wsf,
                                                 const uint16_t* __restrict__ pqb,
                                                 float* __restrict__ part, int nsplit) {
  __shared__ __align__(16) uint16_t Bsm[2][2 * 320 * 32];  // 2 x 40960 B
  const int bid = blockIdx.x;
  const int mblk = bid / nsplit;
  const int ks = bid - mblk * nsplit;
  const int tid = threadIdx.x;
  const int w = tid >> 6, lane = tid & 63;
  const int lr = lane & 15, lg = lane >> 4;
  const int row = mblk * 64 + w * 16 + lr;
  const float c1 = wsf[S1_OFF + row];
  const float s2mx = wsf[SCAL_OFF];
  const float s2mn = wsf[SCAL_OFF + 1];
  float t1 = c1 + s2mx; const float mxp = fmaxf(t1, ALPHA * t1);  // >= all e' in row
  float t2 = c1 + s2mn; const float mn2 = fmaxf(t2, ALPHA * t2);  // <= all e' in row
  const int kcnt = NROW / nsplit;
  const int k0 = ks * kcnt;
  const int ksteps = kcnt >> 5;
  const int tb0 = k0 >> 5;
  const int* adjrow = adj + (size_t)row * NROW;
  f32x4 accP[19], accN[19];
  const f32x4 zero = {0.f, 0.f, 0.f, 0.f};
  #pragma unroll
  for (int ct = 0; ct < 19; ct++) { accP[ct] = zero; accN[ct] = zero; }

  auto STAGE = [&](int b, int tb) {
    const char* tile = (const char*)(pqb + (size_t)tb * 20480);
    char* dst = (char*)Bsm[b];
    #pragma unroll
    for (int it = 0; it < 10; it++) {
      const int off = (w * 10 + it) * 1024;
      __builtin_amdgcn_global_load_lds(
          (const __attribute__((address_space(1))) void*)(tile + off + lane * 16),
          (__attribute__((address_space(3))) void*)(dst + off),
          16, 0, 0);
    }
  };

  // prologue: stage tile 0, prefetch adj/s2 for step 0
  STAGE(0, tb0);
  const int kw0 = k0 + lg * 8;
  int4 cA0 = *(const int4*)(adjrow + kw0);
  int4 cA1 = *(const int4*)(adjrow + kw0 + 4);
  float4 cS0 = *(const float4*)(wsf + S2_OFF + kw0);
  float4 cS1 = *(const float4*)(wsf + S2_OFF + kw0 + 4);
  __syncthreads();

  for (int s = 0; s < ksteps; s++) {
    const int cur = s & 1;
    const int sn = (s + 1 < ksteps) ? s + 1 : s;  // clamp (last iter re-stages, harmless)
    // issue next tile stage + next adj/s2 prefetch (consumed next iteration)
    STAGE(cur ^ 1, tb0 + sn);
    const int kwn = k0 + sn * 32 + lg * 8;
    const int4 nA0 = *(const int4*)(adjrow + kwn);
    const int4 nA1 = *(const int4*)(adjrow + kwn + 4);
    const float4 nS0 = *(const float4*)(wsf + S2_OFF + kwn);
    const float4 nS1 = *(const float4*)(wsf + S2_OFF + kwn + 4);

    // exp/mask/pack for current step (register-only inputs)
    float se[8] = {cS0.x, cS0.y, cS0.z, cS0.w, cS1.x, cS1.y, cS1.z, cS1.w};
    int am[8] = {cA0.x, cA0.y, cA0.z, cA0.w, cA1.x, cA1.y, cA1.z, cA1.w};
    HPack up, un;
    #pragma unroll
    for (int e = 0; e < 8; e += 2) {
      float ea = c1 + se[e];     ea = fmaxf(ea, ALPHA * ea);   // lrelu (log2 domain)
      float eb = c1 + se[e + 1]; eb = fmaxf(eb, ALPHA * eb);
      float pa = exp2f(ea - mxp);
      float pb = exp2f(eb - mxp);
      float na = exp2f(mn2 - ea);
      float nb = exp2f(mn2 - eb);
      pa = am[e] ? pa : 0.0f;     na = am[e] ? na : 0.0f;
      pb = am[e + 1] ? pb : 0.0f; nb = am[e + 1] ? nb : 0.0f;
      up.h2[e >> 1] = __builtin_amdgcn_cvt_pkrtz(pa, pb);
      un.h2[e >> 1] = __builtin_amdgcn_cvt_pkrtz(na, nb);
    }

    const char* smc = (const char*)Bsm[cur];
    #pragma unroll
    for (int ct = 0; ct < 19; ct++) {
      const int col = ct * 16 + lr;
      const int gp = swz(col, lg);
      f16x8 bP = *(const f16x8*)(smc + col * 64 + gp * 16);
      f16x8 bN = *(const f16x8*)(smc + 20480 + col * 64 + gp * 16);
      accP[ct] = __builtin_amdgcn_mfma_f32_16x16x32_f16(up.v, bP, accP[ct], 0, 0, 0);
      accN[ct] = __builtin_amdgcn_mfma_f32_16x16x32_f16(un.v, bN, accN[ct], 0, 0, 0);
    }

    // one barrier per step: drains this step's ds_reads (so next STAGE may
    // overwrite buf[cur]) and the STAGE/prefetch issued above (had full body
    // of VALU+MFMA to land)
    __syncthreads();

    cA0 = nA0; cA1 = nA1; cS0 = nS0; cS1 = nS1;
  }

  const int orow = mblk * 64 + w * 16 + lg * 4;
  float* pbase = part + ((size_t)ks * NROW + orow) * 608;
  #pragma unroll
  for (int ct = 0; ct < 19; ct++) {
    const int col = ct * 16 + lr;
    #pragma unroll
    for (int r = 0; r < 4; r++) {
      pbase[(size_t)r * 608 + col] = accP[ct][r];
      pbase[(size_t)r * 608 + 304 + col] = accN[ct][r];
    }
  }
}

// ---------------- K5: reduce k-splits, normalize, elu ----------------
__global__ void k_final(const float* __restrict__ part, float* __restrict__ out, int nsplit) {
  const int i = blockIdx.x;
  const int t = threadIdx.x;
  if (t >= 300) return;
  float sp = 0.f, sn = 0.f, zp = 0.f, zn = 0.f;
  for (int s = 0; s < nsplit; s++) {
    const float* p = part + ((size_t)s * NROW + i) * 608;
    sp += p[t];
    sn += p[304 + t];
    zp += p[300];
    zn += p[604];
  }
  float x = sp / zp - sn / zn;
  out[(size_t)i * 300 + t] = (x > 0.f) ? x : (exp2f(x * LOG2E) - 1.0f);
}

extern "C" void kernel_launch(void* const* d_in, const int* in_sizes, int n_in,
                              void* d_out, int out_size, void* d_ws, size_t ws_size,
                              hipStream_t stream) {
  const float* inp = (const float*)d_in[0];
  const int* adj = (const int*)d_in[1];
  const float* Wm = (const float*)d_in[2];
  const float* a = (const float*)d_in[3];
  const float* wt = (const float*)d_in[4];
  float* out = (float*)d_out;
  float* wsf = (float*)d_ws;
  uint16_t* pqb = (uint16_t*)((char*)d_ws + PQB_OFF);
  float* part = (float*)((char*)d_ws + PART_OFF);

  int nsplit = 4;
  while (nsplit > 1 &&
         (size_t)PART_OFF + (size_t)nsplit * NROW * 608 * 4 > ws_size)
    nsplit >>= 1;

  k_wa<<<75, 256, 0, stream>>>(Wm, a, wsf);
  k_s12<<<NROW / 4, 256, 0, stream>>>(inp, wsf);
  k_minmax<<<1, 1024, 0, stream>>>(wsf);
  k_wt<<<256, 640, 0, stream>>>(inp, wt, pqb);
  k_main<<<128 * nsplit, 256, 0, stream>>>(adj, wsf, pqb, part, nsplit);
  k_final<<<NROW, 320, 0, stream>>>(part, out, nsplit);
}